// Round 8
// baseline (211.899 us; speedup 1.0000x reference)
//
#include <hip/hip_runtime.h>
#include <hip/hip_fp16.h>
#include <stdint.h>

#define NT 64              // ONE wave per block: blocks self-pace, no barrier coupling
#define RPB 8              // rows per block
#define XSTR 48            // bytes per k-slot (16B data + 32 pad; 12-bank stride -> uniform quads)

// ws layout (byte offsets). Tables per-thread-contiguous: slot = (t&63)*8 + (t>>6)
#define WS_P3   0          // 512 x 8B  {o0|o1<<16, o2|c3h<<16}
#define WS_P4   4096       // 512 x 16B {o0|o1, o2|o3, c4h, 0}
#define WS_P5   12288      // 512 x 16B {o0|o1, o2|o3, o4|c5h, 0}
#define WS_BUTH 20480      // 64x64 halfs: buTh[j*64+i] = (i<j) ? half(b[i][j]) : 0

static __device__ __forceinline__ __half2 H2(unsigned u) {
    return __builtin_bit_cast(__half2, u);
}
static __device__ __forceinline__ unsigned short f2hbits(float f) {
    __half h = __float2half(f);
    return __builtin_bit_cast(unsigned short, h);
}

__global__ void prepack(const float* __restrict__ b,
                        const int* __restrict__ i3, const float* __restrict__ c3,
                        const int* __restrict__ i4, const float* __restrict__ c4,
                        const int* __restrict__ i5, const float* __restrict__ c5,
                        unsigned char* __restrict__ ws)
{
    const int g = blockIdx.x * 256 + threadIdx.x;  // 16 x 256 = 4096
    if (g < 4096) {
        int j = g >> 6, i = g & 63;
        float v = (i < j) ? b[i * 64 + j] : 0.0f;  // transposed strict-upper
        ((unsigned short*)(ws + WS_BUTH))[g] = f2hbits(v);
    }
    if (g < 512) {
        const int slot = (g & 63) * 8 + (g >> 6);  // [ts][m] layout
        unsigned o0, o1, o2, o3, o4;
        o0 = (unsigned)i3[3*g+0] * XSTR; o1 = (unsigned)i3[3*g+1] * XSTR; o2 = (unsigned)i3[3*g+2] * XSTR;
        ((uint2*)(ws + WS_P3))[slot] = make_uint2(o0 | (o1 << 16), o2 | ((unsigned)f2hbits(c3[g]) << 16));
        o0 = (unsigned)i4[4*g+0] * XSTR; o1 = (unsigned)i4[4*g+1] * XSTR;
        o2 = (unsigned)i4[4*g+2] * XSTR; o3 = (unsigned)i4[4*g+3] * XSTR;
        ((uint4*)(ws + WS_P4))[slot] = make_uint4(o0 | (o1 << 16), o2 | (o3 << 16), (unsigned)f2hbits(c4[g]), 0u);
        o0 = (unsigned)i5[5*g+0] * XSTR; o1 = (unsigned)i5[5*g+1] * XSTR;
        o2 = (unsigned)i5[5*g+2] * XSTR; o3 = (unsigned)i5[5*g+3] * XSTR;
        o4 = (unsigned)i5[5*g+4] * XSTR;
        ((uint4*)(ws + WS_P5))[slot] = make_uint4(o0 | (o1 << 16), o2 | (o3 << 16), o4 | ((unsigned)f2hbits(c5[g]) << 16), 0u);
    }
}

static __device__ __forceinline__ void qfma(__half2 bb, uint4 xk, __half2 d[4]) {
    d[0] = __hfma2(bb, H2(xk.x), d[0]);
    d[1] = __hfma2(bb, H2(xk.y), d[1]);
    d[2] = __hfma2(bb, H2(xk.z), d[2]);
    d[3] = __hfma2(bb, H2(xk.w), d[3]);
}
static __device__ __forceinline__ void pmul(const uint4& a, __half2 p[4]) {
    p[0] = __hmul2(p[0], H2(a.x));
    p[1] = __hmul2(p[1], H2(a.y));
    p[2] = __hmul2(p[2], H2(a.z));
    p[3] = __hmul2(p[3], H2(a.w));
}
static __device__ __forceinline__ void pacc(__half2 c2, const __half2 p[4], __half2 acc[4]) {
    acc[0] = __hfma2(c2, p[0], acc[0]);
    acc[1] = __hfma2(c2, p[1], acc[1]);
    acc[2] = __hfma2(c2, p[2], acc[2]);
    acc[3] = __hfma2(c2, p[3], acc[3]);
}

// LDS: 64*48 = 3072 B/block. 4096 single-wave blocks -> up to 16 blocks/CU (VGPR-capped).
__global__ __launch_bounds__(NT, 4)
void poly_main(const float* __restrict__ x, const int* __restrict__ S,
               const float* __restrict__ a,
               const unsigned char* __restrict__ ws, float* __restrict__ out)
{
    __shared__ __align__(16) unsigned char xSb[64 * XSTR];  // [k][8 rows fp16 + pad]

    const int tid  = threadIdx.x;                 // = k for gather, = ts for compute
    const int row0 = blockIdx.x * RPB;

    // ---- batched preload of deg3+deg4 entries (48 VGPRs); e5/bw stream in-loop ----
    uint2 e3[8];
    uint4 e4[8];
    {
        const uint4* s3 = (const uint4*)(ws + WS_P3 + tid * 64);
        #pragma unroll
        for (int i = 0; i < 4; ++i) ((uint4*)e3)[i] = s3[i];
        const uint4* s4 = (const uint4*)(ws + WS_P4 + tid * 128);
        #pragma unroll
        for (int i = 0; i < 8; ++i) e4[i] = s4[i];
    }
    const float av = a[tid];

    // ---- gather: lane k loads column S[k] for 8 rows, packs fp16, one b128 write ----
    {
        const int sk = S[tid];
        const float* xc = x + (size_t)row0 * 1024 + sk;
        float v[8];
        #pragma unroll
        for (int m = 0; m < 8; ++m) v[m] = xc[(size_t)m * 1024];
        uint4 pk;
        pk.x = __builtin_bit_cast(unsigned, __floats2half2_rn(v[0], v[1]));
        pk.y = __builtin_bit_cast(unsigned, __floats2half2_rn(v[2], v[3]));
        pk.z = __builtin_bit_cast(unsigned, __floats2half2_rn(v[4], v[5]));
        pk.w = __builtin_bit_cast(unsigned, __floats2half2_rn(v[6], v[7]));
        *(uint4*)(xSb + tid * XSTR) = pk;
    }
    __syncthreads();   // single wave: compiles to a cheap waitcnt+barrier

    // ---- quad (triangular): d = sum_{i<ts} buT[ts][i]*x_i ; x-reads are loop-uniform
    //      (LDS broadcast, conflict-free); bw streamed from ws (L1-resident) ----
    __half2 d[4] = {H2(0u), H2(0u), H2(0u), H2(0u)};
    {
        const uint4* bwp = (const uint4*)(ws + WS_BUTH + tid * 128);
        const int nii = (tid + 7) >> 3;           // 1..8
        #pragma unroll
        for (int g = 0; g < 8; ++g) {
            if (g < nii) {
                uint4 w4 = bwp[g];
                unsigned pw[4] = {w4.x, w4.y, w4.z, w4.w};
                #pragma unroll
                for (int p = 0; p < 4; ++p) {
                    __half2 blo = __half2half2(__ushort_as_half((unsigned short)(pw[p] & 0xFFFFu)));
                    __half2 bhi = __half2half2(__ushort_as_half((unsigned short)(pw[p] >> 16)));
                    uint4 x0 = *(const uint4*)(xSb + (g * 8 + 2 * p + 0) * XSTR);
                    uint4 x1 = *(const uint4*)(xSb + (g * 8 + 2 * p + 1) * XSTR);
                    qfma(blo, x0, d);
                    qfma(bhi, x1, d);
                }
            }
        }
    }
    __half2 acc[4];
    {
        __half2 a2 = __half2half2(__float2half(av));
        uint4 xj = *(const uint4*)(xSb + tid * XSTR);
        acc[0] = __hmul2(__hadd2(a2, d[0]), H2(xj.x));
        acc[1] = __hmul2(__hadd2(a2, d[1]), H2(xj.y));
        acc[2] = __hmul2(__hadd2(a2, d[2]), H2(xj.z));
        acc[3] = __hmul2(__hadd2(a2, d[3]), H2(xj.w));
    }

    // ---- monomials: 8 per degree; deg3/deg4 from registers, deg5 streamed ----
    #pragma unroll
    for (int m = 0; m < 8; ++m) {
        uint2 p = e3[m];
        uint4 v0 = *(const uint4*)(xSb + (p.x & 0xFFFFu));
        uint4 v1 = *(const uint4*)(xSb + (p.x >> 16));
        uint4 v2 = *(const uint4*)(xSb + (p.y & 0xFFFFu));
        __half2 pr[4] = {H2(v0.x), H2(v0.y), H2(v0.z), H2(v0.w)};
        pmul(v1, pr);
        pmul(v2, pr);
        pacc(__half2half2(__ushort_as_half((unsigned short)(p.y >> 16))), pr, acc);
    }
    #pragma unroll
    for (int m = 0; m < 8; ++m) {
        uint4 p = e4[m];
        uint4 v0 = *(const uint4*)(xSb + (p.x & 0xFFFFu));
        uint4 v1 = *(const uint4*)(xSb + (p.x >> 16));
        uint4 v2 = *(const uint4*)(xSb + (p.y & 0xFFFFu));
        uint4 v3 = *(const uint4*)(xSb + (p.y >> 16));
        __half2 pr[4] = {H2(v0.x), H2(v0.y), H2(v0.z), H2(v0.w)};
        pmul(v1, pr);
        pmul(v2, pr);
        pmul(v3, pr);
        pacc(__half2half2(__ushort_as_half((unsigned short)(p.z & 0xFFFFu))), pr, acc);
    }
    {
        const uint4* p5 = (const uint4*)(ws + WS_P5 + tid * 128);
        #pragma unroll 4
        for (int m = 0; m < 8; ++m) {
            uint4 p = p5[m];
            uint4 v0 = *(const uint4*)(xSb + (p.x & 0xFFFFu));
            uint4 v1 = *(const uint4*)(xSb + (p.x >> 16));
            uint4 v2 = *(const uint4*)(xSb + (p.y & 0xFFFFu));
            uint4 v3 = *(const uint4*)(xSb + (p.y >> 16));
            uint4 v4 = *(const uint4*)(xSb + (p.z & 0xFFFFu));
            __half2 pr[4] = {H2(v0.x), H2(v0.y), H2(v0.z), H2(v0.w)};
            pmul(v1, pr);
            pmul(v2, pr);
            pmul(v3, pr);
            pmul(v4, pr);
            pacc(__half2half2(__ushort_as_half((unsigned short)(p.z >> 16))), pr, acc);
        }
    }

    // ---- reduce across the wave (all 64 ts slices), fp32 butterfly ----
    float f[8];
    #pragma unroll
    for (int e = 0; e < 4; ++e) {
        f[2 * e]     = __low2float(acc[e]);
        f[2 * e + 1] = __high2float(acc[e]);
    }
    #pragma unroll
    for (int mask = 1; mask <= 32; mask <<= 1) {
        #pragma unroll
        for (int r = 0; r < 8; ++r) f[r] += __shfl_xor(f[r], mask, 64);
    }
    if (tid == 0) {
        *(float4*)(out + row0)     = make_float4(f[0], f[1], f[2], f[3]);
        *(float4*)(out + row0 + 4) = make_float4(f[4], f[5], f[6], f[7]);
    }
}

extern "C" void kernel_launch(void* const* d_in, const int* in_sizes, int n_in,
                              void* d_out, int out_size, void* d_ws, size_t ws_size,
                              hipStream_t stream) {
    const float* x  = (const float*)d_in[0];
    const int*   S  = (const int*)d_in[1];
    const float* a  = (const float*)d_in[2];
    const float* b  = (const float*)d_in[3];
    const int*   i3 = (const int*)d_in[4];
    const float* c3 = (const float*)d_in[5];
    const int*   i4 = (const int*)d_in[6];
    const float* c4 = (const float*)d_in[7];
    const int*   i5 = (const int*)d_in[8];
    const float* c5 = (const float*)d_in[9];
    unsigned char* ws = (unsigned char*)d_ws;
    float* out = (float*)d_out;

    prepack<<<16, 256, 0, stream>>>(b, i3, c3, i4, c4, i5, c5, ws);
    poly_main<<<32768 / RPB, NT, 0, stream>>>(x, S, a, ws, out);
}